// Round 2
// baseline (355.505 us; speedup 1.0000x reference)
//
#include <hip/hip_runtime.h>

#define HID 896
#define NH 14
#define NKV 2
#define NREP 7
#define SEQ 2048
#define BT 2
#define NTOK (BT*SEQ)
#define CSCALE 0.18033688011112042f   // (1/8) * log2(e)

typedef __attribute__((ext_vector_type(8))) short bf16x8;
typedef __attribute__((ext_vector_type(8))) unsigned short u16x8;
typedef __attribute__((ext_vector_type(4))) float fx4;

__device__ __forceinline__ unsigned short f2b(float x){
  union { float f; unsigned u; } a; a.f = x;
  unsigned r = a.u + 0x7FFFu + ((a.u >> 16) & 1u);   // RNE
  return (unsigned short)(r >> 16);
}

// ---------------- fused QKV projection + bias + RoPE ----------------
// grid (NTOK/64, 18), block 256. bn 0..13 -> Q head; 14,15 -> K; 16,17 -> V (stored transposed)
__global__ __launch_bounds__(256) void qkv_rope_kernel(
    const float* __restrict__ hidden, const int* __restrict__ pos,
    const float* __restrict__ Wq, const float* __restrict__ bq,
    const float* __restrict__ Wk, const float* __restrict__ bk,
    const float* __restrict__ Wv, const float* __restrict__ bv,
    unsigned short* __restrict__ qo, unsigned short* __restrict__ ko,
    unsigned short* __restrict__ vt)
{
  __shared__ short As[64*40];
  __shared__ short Bs[64*40];
  const int tid = threadIdx.x;
  const int bm = blockIdx.x, bn = blockIdx.y;
  const int w = tid >> 6, l = tid & 63, l15 = l & 15, l16 = l >> 4;

  const float *W, *bias; int kind, hloc;
  if (bn < NH)      { W = Wq + (size_t)bn*64*HID;      bias = bq + bn*64;      kind = 0; hloc = bn; }
  else if (bn < 16) { W = Wk + (size_t)(bn-NH)*64*HID; bias = bk + (bn-NH)*64; kind = 1; hloc = bn-NH; }
  else              { W = Wv + (size_t)(bn-16)*64*HID; bias = bv + (bn-16)*64; kind = 2; hloc = bn-16; }

  fx4 acc[4] = {{0,0,0,0},{0,0,0,0},{0,0,0,0},{0,0,0,0}};

  const int r = tid >> 2, c8 = (tid & 3) * 8;
  const float* ap0 = hidden + (size_t)(bm*64 + r)*HID + c8;
  const float* bp0 = W + (size_t)r*HID + c8;

  for (int kc = 0; kc < HID; kc += 32){
    __syncthreads();
    float4 a0 = *(const float4*)(ap0 + kc);
    float4 a1 = *(const float4*)(ap0 + kc + 4);
    float4 b0 = *(const float4*)(bp0 + kc);
    float4 b1 = *(const float4*)(bp0 + kc + 4);
    bf16x8 avv, bvv;
    avv[0]=(short)f2b(a0.x); avv[1]=(short)f2b(a0.y); avv[2]=(short)f2b(a0.z); avv[3]=(short)f2b(a0.w);
    avv[4]=(short)f2b(a1.x); avv[5]=(short)f2b(a1.y); avv[6]=(short)f2b(a1.z); avv[7]=(short)f2b(a1.w);
    bvv[0]=(short)f2b(b0.x); bvv[1]=(short)f2b(b0.y); bvv[2]=(short)f2b(b0.z); bvv[3]=(short)f2b(b0.w);
    bvv[4]=(short)f2b(b1.x); bvv[5]=(short)f2b(b1.y); bvv[6]=(short)f2b(b1.z); bvv[7]=(short)f2b(b1.w);
    *(bf16x8*)&As[r*40 + c8] = avv;
    *(bf16x8*)&Bs[r*40 + c8] = bvv;
    __syncthreads();
    bf16x8 af = *(bf16x8*)&As[(w*16 + l15)*40 + l16*8];
#pragma unroll
    for (int nt = 0; nt < 4; nt++){
      bf16x8 bfr = *(bf16x8*)&Bs[(nt*16 + l15)*40 + l16*8];
      acc[nt] = __builtin_amdgcn_mfma_f32_16x16x32_bf16(af, bfr, acc[nt], 0, 0, 0);
    }
  }

  float bl[4];
#pragma unroll
  for (int nt = 0; nt < 4; nt++) bl[nt] = bias[nt*16 + l15];

  if (kind == 2){
    // V stored TRANSPOSED: (B, NKV, D=64, SEQ) so attn can load B-frags directly
#pragma unroll
    for (int j = 0; j < 4; j++){
      int grow = bm*64 + w*16 + l16*4 + j;
      int b = grow >> 11, s = grow & (SEQ-1);
      unsigned short* dst = vt + ((size_t)(b*NKV + hloc)*64)*SEQ + s;
#pragma unroll
      for (int nt = 0; nt < 4; nt++)
        dst[(size_t)(nt*16 + l15)*SEQ] = f2b(acc[nt][j] + bl[nt]);
    }
  } else {
    float invf[2];
#pragma unroll
    for (int nt = 0; nt < 2; nt++)
      invf[nt] = exp2f(-(float)(nt*16 + l15) * 0.62286151779138041f);
#pragma unroll
    for (int j = 0; j < 4; j++){
      int grow = bm*64 + w*16 + l16*4 + j;
      int b = grow >> 11, s = grow & (SEQ-1);
      float p = (float)pos[grow];
      unsigned short* dst = (kind == 0)
          ? qo + ((size_t)(b*NH  + hloc)*SEQ + s)*64
          : ko + ((size_t)(b*NKV + hloc)*SEQ + s)*64;
#pragma unroll
      for (int nt = 0; nt < 2; nt++){
        int d = nt*16 + l15;
        float f = p * invf[nt];
        float sv, cv;
        sincosf(f, &sv, &cv);
        float x1 = acc[nt][j]   + bl[nt];
        float x2 = acc[nt+2][j] + bl[nt+2];
        dst[d]    = f2b(x1*cv - x2*sv);
        dst[d+32] = f2b(x2*cv + x1*sv);
      }
    }
  }
}

// ---------------- flash attention v2: barrier-free K-loop ----------------
// grid (SEQ/64, NH, BT), block 256 (4 independent waves; wave w owns q rows bq0+16w..+16).
// K frags loaded direct from global (natural K layout); V frags direct from V^T layout.
// LDS only for the per-wave P C-layout -> A-layout round trip.
__global__ __launch_bounds__(256) void attn_kernel(
    const unsigned short* __restrict__ q, const unsigned short* __restrict__ k,
    const unsigned short* __restrict__ vt, unsigned short* __restrict__ ao)
{
  __shared__ short Ps[4][16*72];   // per-wave; row stride 72 shorts (144B, 16B-aligned)

  const int tid = threadIdx.x;
  const int w = tid >> 6, l = tid & 63, l15 = l & 15, l16 = l >> 4;
  const int t = blockIdx.x, h = blockIdx.y, b = blockIdx.z, kvh = h / NREP;
  const int bq0 = t*64;

  const int qrow = bq0 + w*16 + l15;
  const unsigned short* qp = q + ((size_t)(b*NH + h)*SEQ + qrow)*64;
  bf16x8 qf0 = *(const bf16x8*)(qp + l16*8);
  bf16x8 qf1 = *(const bf16x8*)(qp + 32 + l16*8);

  fx4 o[4] = {{0,0,0,0},{0,0,0,0},{0,0,0,0},{0,0,0,0}};
  float m_run[4] = {-1e30f,-1e30f,-1e30f,-1e30f};
  float l_run[4] = {0.f,0.f,0.f,0.f};

  const unsigned short* kbase  = k  + ((size_t)(b*NKV + kvh)*SEQ)*64;
  const unsigned short* vtbase = vt + ((size_t)(b*NKV + kvh)*64)*SEQ;
  short* myP = &Ps[w][0];

  for (int kt = 0; kt <= t; kt++){
    const int key0 = kt*64;
    const bool diag = (kt == t);

    // S = Q K^T : 16 q-rows x 64 keys per wave, K frags direct from global
    fx4 s[4] = {{0,0,0,0},{0,0,0,0},{0,0,0,0},{0,0,0,0}};
#pragma unroll
    for (int nt = 0; nt < 4; nt++){
      const unsigned short* kp = kbase + (size_t)(key0 + nt*16 + l15)*64;
      bf16x8 kf0 = *(const bf16x8*)(kp + l16*8);
      bf16x8 kf1 = *(const bf16x8*)(kp + 32 + l16*8);
      s[nt] = __builtin_amdgcn_mfma_f32_16x16x32_bf16(qf0, kf0, s[nt], 0,0,0);
      s[nt] = __builtin_amdgcn_mfma_f32_16x16x32_bf16(qf1, kf1, s[nt], 0,0,0);
    }

    // online softmax over 64 keys (per j-row: 4 regs x 16 lanes)
    float alpha[4];
#pragma unroll
    for (int j = 0; j < 4; j++){
      float tv[4];
#pragma unroll
      for (int nt = 0; nt < 4; nt++){
        float x = s[nt][j]*CSCALE;                 // log2-domain, scale folded
        if (diag) x = (nt*16 + l15 <= w*16 + l16*4 + j) ? x : -1e30f;
        tv[nt] = x;
      }
      float mx = fmaxf(fmaxf(tv[0],tv[1]), fmaxf(tv[2],tv[3]));
      mx = fmaxf(mx, __shfl_xor(mx, 1)); mx = fmaxf(mx, __shfl_xor(mx, 2));
      mx = fmaxf(mx, __shfl_xor(mx, 4)); mx = fmaxf(mx, __shfl_xor(mx, 8));
      float mn = fmaxf(m_run[j], mx);
      float al = exp2f(m_run[j] - mn);
      m_run[j] = mn;
      float p0 = exp2f(tv[0] - mn), p1 = exp2f(tv[1] - mn);
      float p2 = exp2f(tv[2] - mn), p3 = exp2f(tv[3] - mn);
      float rs = (p0 + p1) + (p2 + p3);
      rs += __shfl_xor(rs, 1); rs += __shfl_xor(rs, 2);
      rs += __shfl_xor(rs, 4); rs += __shfl_xor(rs, 8);
      l_run[j] = l_run[j]*al + rs;
      alpha[j] = al;
      const int row = l16*4 + j;
      myP[row*72 +      l15] = (short)f2b(p0);
      myP[row*72 + 16 + l15] = (short)f2b(p1);
      myP[row*72 + 32 + l15] = (short)f2b(p2);
      myP[row*72 + 48 + l15] = (short)f2b(p3);
    }
#pragma unroll
    for (int nt = 0; nt < 4; nt++)
#pragma unroll
      for (int j = 0; j < 4; j++) o[nt][j] *= alpha[j];

    asm volatile("s_waitcnt lgkmcnt(0)" ::: "memory");  // wave-local LDS ordering
    bf16x8 pa0 = *(bf16x8*)&myP[l15*72 + l16*8];        // P A-frag, keys 0..31
    bf16x8 pa1 = *(bf16x8*)&myP[l15*72 + 32 + l16*8];   // keys 32..63

    // O += P V : V frags direct from global V^T
#pragma unroll
    for (int nt = 0; nt < 4; nt++){
      const unsigned short* vp = vtbase + (size_t)(nt*16 + l15)*SEQ + key0;
      bf16x8 vb0 = *(const bf16x8*)(vp + l16*8);
      bf16x8 vb1 = *(const bf16x8*)(vp + 32 + l16*8);
      o[nt] = __builtin_amdgcn_mfma_f32_16x16x32_bf16(pa0, vb0, o[nt], 0,0,0);
      o[nt] = __builtin_amdgcn_mfma_f32_16x16x32_bf16(pa1, vb1, o[nt], 0,0,0);
    }
  }

#pragma unroll
  for (int j = 0; j < 4; j++){
    int qg = bq0 + w*16 + l16*4 + j;
    float inv = 1.0f / l_run[j];
    unsigned short* dst = ao + ((size_t)(b*SEQ + qg))*HID + h*64;
#pragma unroll
    for (int nt = 0; nt < 4; nt++)
      dst[nt*16 + l15] = f2b(o[nt][j] * inv);
  }
}

// ---------------- output projection: attn(bf16) @ Wo^T -> fp32 ----------------
// grid (NTOK/64, 14), block 256
__global__ __launch_bounds__(256) void out_gemm_kernel(
    const unsigned short* __restrict__ A, const float* __restrict__ Wo,
    float* __restrict__ out)
{
  __shared__ short As[64*40];
  __shared__ short Bs[64*40];
  const int tid = threadIdx.x;
  const int bm = blockIdx.x, bn = blockIdx.y;
  const int w = tid >> 6, l = tid & 63, l15 = l & 15, l16 = l >> 4;

  fx4 acc[4] = {{0,0,0,0},{0,0,0,0},{0,0,0,0},{0,0,0,0}};
  const int r = tid >> 2, c8 = (tid & 3)*8;
  const unsigned short* ap0 = A + (size_t)(bm*64 + r)*HID + c8;
  const float* bp0 = Wo + (size_t)(bn*64 + r)*HID + c8;

  for (int kc = 0; kc < HID; kc += 32){
    __syncthreads();
    u16x8 a8 = *(const u16x8*)(ap0 + kc);
    float4 b0 = *(const float4*)(bp0 + kc);
    float4 b1 = *(const float4*)(bp0 + kc + 4);
    bf16x8 bvv;
    bvv[0]=(short)f2b(b0.x); bvv[1]=(short)f2b(b0.y); bvv[2]=(short)f2b(b0.z); bvv[3]=(short)f2b(b0.w);
    bvv[4]=(short)f2b(b1.x); bvv[5]=(short)f2b(b1.y); bvv[6]=(short)f2b(b1.z); bvv[7]=(short)f2b(b1.w);
    *(u16x8*)&As[r*40 + c8] = a8;
    *(bf16x8*)&Bs[r*40 + c8] = bvv;
    __syncthreads();
    bf16x8 af = *(bf16x8*)&As[(w*16 + l15)*40 + l16*8];
#pragma unroll
    for (int nt = 0; nt < 4; nt++){
      bf16x8 bfr = *(bf16x8*)&Bs[(nt*16 + l15)*40 + l16*8];
      acc[nt] = __builtin_amdgcn_mfma_f32_16x16x32_bf16(af, bfr, acc[nt], 0, 0, 0);
    }
  }

#pragma unroll
  for (int j = 0; j < 4; j++){
    int grow = bm*64 + w*16 + l16*4 + j;
    float* dst = out + (size_t)grow*HID + bn*64;
#pragma unroll
    for (int nt = 0; nt < 4; nt++)
      dst[nt*16 + l15] = acc[nt][j];
  }
}

extern "C" void kernel_launch(void* const* d_in, const int* in_sizes, int n_in,
                              void* d_out, int out_size, void* d_ws, size_t ws_size,
                              hipStream_t stream)
{
  const float* hidden = (const float*)d_in[0];
  const int*   pos    = (const int*)d_in[1];
  const float* Wq = (const float*)d_in[2]; const float* bq = (const float*)d_in[3];
  const float* Wk = (const float*)d_in[4]; const float* bk = (const float*)d_in[5];
  const float* Wv = (const float*)d_in[6]; const float* bv = (const float*)d_in[7];
  const float* Wo = (const float*)d_in[8];

  unsigned short* qws  = (unsigned short*)d_ws;                      // (B,NH,S,64) bf16
  unsigned short* kws  = qws + (size_t)BT*NH*SEQ*64;                 // (B,NKV,S,64)
  unsigned short* vtws = kws + (size_t)BT*NKV*SEQ*64;                // (B,NKV,64,S)  V^T
  unsigned short* aws  = vtws + (size_t)BT*NKV*SEQ*64;               // (B,S,896) bf16

  qkv_rope_kernel<<<dim3(NTOK/64, 18), 256, 0, stream>>>(
      hidden, pos, Wq, bq, Wk, bk, Wv, bv, qws, kws, vtws);
  attn_kernel<<<dim3(SEQ/64, NH, BT), 256, 0, stream>>>(qws, kws, vtws, aws);
  out_gemm_kernel<<<dim3(NTOK/64, NH), 256, 0, stream>>>(aws, Wo, (float*)d_out);
}